// Round 10
// baseline (358.902 us; speedup 1.0000x reference)
//
#include <hip/hip_runtime.h>
#include <math.h>
#include <stdint.h>

// SoftAttention B=32, L=1024, D=256 fp32 via split-bf16 MFMA flash attention.
// R13 = R12 + UNIFORM TILE COUNT (the one isolated change).
// R12 post-mortem: removing the scattered K staging did NOT reduce FETCH
// (226 vs R11's 228 MB) -> the 2x fetch was never the scatter. New theory:
// variable per-pair ntiles (compaction) makes block durations non-uniform;
// round-2 of the 512-block/256-CU schedule assigns blocks to first-free CUs,
// scrambling the bx&7 -> XCD pin -> round-2 pairs re-fetch K/V per block
// (2x avg fetch, staging at L3 latency, per-tile 6.7->12us). Fix: all blocks
// run gnt = ceil(max_nv/64) tiles (padded tiles are zero-filled in Kc/T and
// mkv=0 -> contribute nothing). Uniform duration restores R6's round-2
// alignment at ~9/16 of R6's work.

#define NB    32
#define SEQ   1024
#define DIM   256
#define BM    128
#define BN    64
#define SHIFT 60.0f
#define PS    1048   // Ph ushort stride per koct: b128-aligned, bank-spread

typedef unsigned int uint;
typedef unsigned short ushort;
typedef __attribute__((ext_vector_type(8)))  short short8;
typedef __attribute__((ext_vector_type(16))) float f32x16;

// ws layout (ushort units for tensors, then int arrays)
#define KC_BATCH  (64 * 1024 * 8)            // [dimoct64][ckey1024][8] (hi 0..31, lo 32..63)
#define KC_TENSOR ((size_t)NB * KC_BATCH)    // 32 MB
#define T_BATCH   (128 * 256 * 8)            // [ckeyoct128][dim256][8]
#define T_TENSOR  ((size_t)NB * T_BATCH)     // 16 MB
#define IDX_INTS  ((size_t)NB * SEQ)
#define WS_NEED   ((2 * KC_TENSOR + 2 * T_TENSOR) * sizeof(ushort) + (2 * IDX_INTS + 64) * sizeof(int))

__device__ __forceinline__ ushort bf16_rn(float x) {
    union { float f; uint u; } v; v.f = x;
    uint r = v.u + 0x7fffu + ((v.u >> 16) & 1u);
    return (ushort)(r >> 16);
}
__device__ __forceinline__ float bf16_to_f(ushort h) {
    union { uint u; float f; } v; v.u = ((uint)h) << 16;
    return v.f;
}
__device__ __forceinline__ void gl_lds16(const ushort* g, ushort* l) {
    __builtin_amdgcn_global_load_lds(
        (const __attribute__((address_space(1))) void*)g,
        (__attribute__((address_space(3))) void*)l, 16, 0, 0);
}

// ---------------- mask compaction: prefix-sum -> idx list + count ----------------
__global__ __launch_bounds__(1024)
void compact(const int* __restrict__ ma, const int* __restrict__ mb,
             int* __restrict__ idxA, int* __restrict__ idxB, int* __restrict__ nvArr)
{
    const int batch = blockIdx.x;
    const int t     = blockIdx.y;            // 0: ma->idxA, 1: mb->idxB
    const int* m = t ? mb : ma;
    int* idx = (t ? idxB : idxA) + batch * SEQ;
    const int tid = threadIdx.x;             // 0..1023
    const int lane = tid & 63, wv = tid >> 6;

    __shared__ int wsum[16];
    __shared__ int base[17];

    int v = (m[batch * SEQ + tid] != 0) ? 1 : 0;
    unsigned long long bal = __ballot(v);
    int lanePre = __popcll(bal & ((1ULL << lane) - 1ULL));
    if (lane == 0) wsum[wv] = __popcll(bal);
    __syncthreads();
    if (tid == 0) {
        int acc = 0;
        #pragma unroll
        for (int w = 0; w < 16; ++w) { base[w] = acc; acc += wsum[w]; }
        base[16] = acc;
        nvArr[t * NB + batch] = acc;
    }
    __syncthreads();
    if (v) idx[base[wv] + lanePre] = tid;
    if (tid >= base[16]) idx[tid] = 0;       // pad (never addressed: gathers guard on nv)
}

// ---------------- gatherK: fp32 rows -> compacted hi/lo bf16 K tensor ----------------
// block = one compacted oct (8 keys x 256 dims); thread=(oct 0..31, srow 0..7).
// Zero-fills keys >= nv (NaN-safe; masked out by mkv anyway).
__global__ __launch_bounds__(256)
void gatherK(const float* __restrict__ A, const float* __restrict__ Bt,
             const int* __restrict__ idxA, const int* __restrict__ idxB,
             const int* __restrict__ nvArr,
             ushort* __restrict__ aKc, ushort* __restrict__ bKc)
{
    const int z     = blockIdx.z;            // 0: aKc from A/idxA, 1: bKc from B/idxB
    const int batch = blockIdx.y;
    const int soct  = blockIdx.x;            // 0..127 compacted oct
    const float* src = z ? Bt : A;
    const int* idx = (z ? idxB : idxA) + batch * SEQ;
    const int nv = nvArr[z * NB + batch];
    ushort* kcb = (z ? bKc : aKc) + (size_t)batch * KC_BATCH;

    const int tid = threadIdx.x;
    const int oct = tid >> 3, srow = tid & 7;
    const int c = soct * 8 + srow;           // compacted key index

    float xs[8] = {0.f, 0.f, 0.f, 0.f, 0.f, 0.f, 0.f, 0.f};
    if (c < nv) {
        const float* rp = src + ((size_t)batch * SEQ + idx[c]) * DIM + oct * 8;
        float4 x0 = *(const float4*)rp;
        float4 x1 = *(const float4*)(rp + 4);
        xs[0]=x0.x; xs[1]=x0.y; xs[2]=x0.z; xs[3]=x0.w;
        xs[4]=x1.x; xs[5]=x1.y; xs[6]=x1.z; xs[7]=x1.w;
    }
    short8 hv, lv;
    #pragma unroll
    for (int j = 0; j < 8; ++j) {
        ushort h = bf16_rn(xs[j]);
        hv[j] = (short)h;
        lv[j] = (short)bf16_rn(xs[j] - bf16_to_f(h));
    }
    *(short8*)(kcb + (size_t)oct * 8192 + (size_t)c * 8)        = hv;
    *(short8*)(kcb + (size_t)(oct + 32) * 8192 + (size_t)c * 8) = lv;
}

// ---------------- gatherT: V tensors (hi) in compacted key order ----------------
__global__ __launch_bounds__(256)
void gatherT(const float* __restrict__ A, const float* __restrict__ Bt,
             const int* __restrict__ idxA, const int* __restrict__ idxB,
             const int* __restrict__ nvArr,
             ushort* __restrict__ aT, ushort* __restrict__ bT)
{
    const int z     = blockIdx.z;
    const int batch = blockIdx.y;
    const int soct  = blockIdx.x;            // 0..127 (compacted)
    const float* src = z ? Bt : A;
    const int* idx = (z ? idxB : idxA) + batch * SEQ;
    const int nv = nvArr[z * NB + batch];
    ushort* tp = (z ? bT : aT) + (size_t)batch * T_BATCH + (size_t)soct * 2048;
    const int d = threadIdx.x;               // 0..255
    short8 hv;
    #pragma unroll
    for (int j = 0; j < 8; ++j) {
        int c = soct * 8 + j;
        float x = 0.f;
        if (c < nv) x = src[((size_t)batch * SEQ + idx[c]) * DIM + d];
        hv[j] = (short)bf16_rn(x);
    }
    *(short8*)(tp + (size_t)d * 8) = hv;
}

// ---------------- main kernel: both directions, 512 threads, XCD-pinned ----------------
__global__ __launch_bounds__(512, 2)
void attend3(const float*  __restrict__ A,   const float*  __restrict__ Bt,
             const ushort* __restrict__ aKc, const ushort* __restrict__ bKc,
             const ushort* __restrict__ aT,  const ushort* __restrict__ bT,
             const int*    __restrict__ nvArr,
             const int*    __restrict__ ma,  const int*    __restrict__ mb,
             float*        __restrict__ out)
{
    __shared__ __align__(16) ushort Ks2[64 * 512];   // [dimoct64][key64][8] 64 KB
    __shared__ __align__(16) ushort Vt2[8 * 2048];   // [koct8][dim256][8]   32 KB
    __shared__ __align__(16) ushort Ph[8 * PS];      // [koct8][qrow128][8]  16.4 KB
    __shared__ float lpart[2][BM];
    __shared__ float invs[BM];

    // XCD-pinning swizzle: all 8 row-blocks of one (batch,dir) pair share an XCD.
    const int bx   = blockIdx.x;        // 0..511
    const int xcd  = bx & 7;
    const int slot = bx >> 3;           // 0..63
    const int rb   = slot & 7;          // row-block 0..7
    const int pg   = slot >> 3;         // 0..7
    const int pair = xcd + 8 * pg;      // 0..63, pair%8 == xcd
    const int batch = pair >> 1;
    const int dir   = pair & 1;
    const int row0  = rb * BM;

    const float*  qsrc = dir ? Bt  : A;      // Q rows from fp32 source
    const ushort* kcY  = dir ? aKc : bKc;    // compacted K (hi/lo)
    const ushort* tY   = dir ? aT  : bT;     // compacted V (hi)
    const int*    mx   = dir ? mb  : ma;
    const int     nv   = nvArr[(dir ? 0 : 1) * NB + batch];
    float* o = out + (size_t)dir * NB * SEQ * DIM;

    // UNIFORM tile count across ALL pairs: identical block duration ->
    // round-2 block->CU assignment preserves the XCD pin (R12 post-mortem).
    int gmax = 0;
    for (int i = 0; i < 64; ++i) { int t = nvArr[i]; gmax = t > gmax ? t : gmax; }
    int gnt = (gmax + BN - 1) >> 6;
    if (gnt < 1) gnt = 1;

    const int tid  = threadIdx.x;
    const int lane = tid & 63;
    const int wave = tid >> 6;     // 0..7
    const int l31  = lane & 31;
    const int lh   = lane >> 5;
    const int rw   = wave >> 1;    // 0..3 (row block)
    const int cw   = wave & 1;     // 0..1 (key half / dim half)

    const ushort* kcYb = kcY + (size_t)batch * KC_BATCH;
    const ushort* tYb  = tY  + (size_t)batch * T_BATCH;

    // staging bases: wave w stages K dimocts w*8..w*8+7 and V koct w (all linear)
    const ushort* ksrc = kcYb + (size_t)(wave * 8) * 8192 + (size_t)lane * 8;
    ushort*       kdst = Ks2 + wave * 8 * 512 + lane * 8;
    const ushort* vsrc = tYb + (size_t)wave * 2048 + (size_t)lane * 8;
    ushort*       vdst = Vt2 + wave * 2048 + lane * 8;

    // issue K(0), V(0)
    #pragma unroll
    for (int i = 0; i < 8; ++i) gl_lds16(ksrc + (size_t)i * 8192, kdst + i * 512);
    #pragma unroll
    for (int i = 0; i < 4; ++i) gl_lds16(vsrc + i * 512, vdst + i * 512);

    // Q fragments (hi+lo) straight from fp32 global (once per block; latency
    // hides under K/V staging). Same pattern as the known-good fallback.
    const int qrow = row0 + rw * 32 + l31;
    short8 qhi[16], qlo[16];
    {
        const float* qp = qsrc + ((size_t)batch * SEQ + qrow) * DIM + lh * 8;
        #pragma unroll
        for (int kk = 0; kk < 16; ++kk) {
            const float* p = qp + kk * 16;
            float4 x0 = *(const float4*)p;
            float4 x1 = *(const float4*)(p + 4);
            float xs[8] = {x0.x, x0.y, x0.z, x0.w, x1.x, x1.y, x1.z, x1.w};
            #pragma unroll
            for (int j = 0; j < 8; ++j) {
                ushort h = bf16_rn(xs[j]);
                qhi[kk][j] = (short)h;
                qlo[kk][j] = (short)bf16_rn(xs[j] - bf16_to_f(h));
            }
        }
    }

    f32x16 oacc[4];
    #pragma unroll
    for (int t = 0; t < 4; ++t)
        #pragma unroll
        for (int r = 0; r < 16; ++r) oacc[t][r] = 0.f;
    float lsum[16];
    #pragma unroll
    for (int r = 0; r < 16; ++r) lsum[r] = 0.f;

    __syncthreads();   // drains K(0), V(0)

    for (int nt = 0; nt < gnt; ++nt) {
        const int key0 = nt * BN;
        const float mkv = (key0 + cw * 32 + l31 < nv) ? 1.f : 0.f;

        // ---- S phase: a1 = Qhi·Khi ; a2 = Qlo·Khi + Qhi·Klo ----
        f32x16 a1, a2;
        #pragma unroll
        for (int r = 0; r < 16; ++r) { a1[r] = 0.f; a2[r] = 0.f; }
        const int kcol = (cw * 32 + l31) * 8;
        #pragma unroll
        for (int kk = 0; kk < 16; ++kk) {
            short8 bhi = *(const short8*)&Ks2[(2 * kk + lh) * 512 + kcol];
            a1 = __builtin_amdgcn_mfma_f32_32x32x16_bf16(qhi[kk], bhi, a1, 0, 0, 0);
            a2 = __builtin_amdgcn_mfma_f32_32x32x16_bf16(qlo[kk], bhi, a2, 0, 0, 0);
        }
        #pragma unroll
        for (int kk = 0; kk < 16; ++kk) {
            short8 blo = *(const short8*)&Ks2[(2 * kk + lh + 32) * 512 + kcol];
            a2 = __builtin_amdgcn_mfma_f32_32x32x16_bf16(qhi[kk], blo, a2, 0, 0, 0);
        }

        // ---- fixed-shift exp, l-partials, pack P-hi to LDS ----
        const int key  = cw * 32 + l31;
        const int koct = key >> 3, kj = key & 7;
        #pragma unroll
        for (int r = 0; r < 16; ++r) {
            float s = a1[r] + a2[r];
            float p = __expf(s - SHIFT) * mkv;
            lsum[r] += p;
            int qr = rw * 32 + (r & 3) + ((r >> 2) << 3) + (lh << 2);
            Ph[koct * PS + qr * 8 + kj] = bf16_rn(p);
        }
        __syncthreads();   // P visible; Ks2 free

        // prefetch K(nt+1) — linear compacted stream, flies during PV
        if (nt + 1 < gnt) {
            const ushort* ks = ksrc + (size_t)(key0 + BN) * 8;
            #pragma unroll
            for (int i = 0; i < 8; ++i) gl_lds16(ks + (size_t)i * 8192, kdst + i * 512);
        }

        // ---- PV phase: oacc += Phi·Vhi ----
        const int prow = (rw * 32 + l31) * 8;
        #pragma unroll
        for (int kb = 0; kb < 4; ++kb) {
            short8 pa = *(const short8*)&Ph[(2 * kb + lh) * PS + prow];
            #pragma unroll
            for (int t = 0; t < 4; ++t) {
                int dim = cw * 128 + t * 32 + l31;
                short8 vf = *(const short8*)&Vt2[(2 * kb + lh) * 2048 + dim * 8];
                oacc[t] = __builtin_amdgcn_mfma_f32_32x32x16_bf16(pa, vf, oacc[t], 0, 0, 0);
            }
        }
        __syncthreads();   // Vt2/Ph free; drains K(nt+1)

        // prefetch V(nt+1) — flies during next S phase
        if (nt + 1 < gnt) {
            const ushort* vs = vsrc + ((size_t)(key0 + BN) >> 3) * 2048;
            #pragma unroll
            for (int i = 0; i < 4; ++i) gl_lds16(vs + i * 512, vdst + i * 512);
        }
    }

    // ---- epilogue: reduce l, normalize, store ----
    #pragma unroll
    for (int r = 0; r < 16; ++r) {
        float v = lsum[r];
        v += __shfl_xor(v, 1, 64);
        v += __shfl_xor(v, 2, 64);
        v += __shfl_xor(v, 4, 64);
        v += __shfl_xor(v, 8, 64);
        v += __shfl_xor(v, 16, 64);
        if (l31 == 0) {
            int row = rw * 32 + (r & 3) + ((r >> 2) << 3) + (lh << 2);
            lpart[cw][row] = v;
        }
    }
    __syncthreads();
    if (tid < BM) {
        float l = lpart[0][tid] + lpart[1][tid];
        int valid = mx[batch * SEQ + row0 + tid];
        invs[tid] = (valid != 0 && l > 0.f) ? 1.f / l : 0.f;
    }
    __syncthreads();

    float* ob = o + ((size_t)batch * SEQ + row0) * DIM;
    #pragma unroll
    for (int r = 0; r < 16; ++r) {
        int rloc = rw * 32 + (r & 3) + ((r >> 2) << 3) + (lh << 2);
        float inv = invs[rloc];
        #pragma unroll
        for (int t = 0; t < 4; ++t) {
            int d = cw * 128 + t * 32 + l31;
            ob[(size_t)rloc * DIM + d] = oacc[t][r] * inv;
        }
    }
}

// ---------------- fallback (R2 kernel, known-good) if ws too small ----------------
#define F_KS_STR 520
#define F_P_STR  136
#define F_BM 64
#define F_BN 64
__global__ __launch_bounds__(256, 1)
void attend_mfma(const float* __restrict__ X, const float* __restrict__ Y,
                 const int* __restrict__ mx, const int* __restrict__ my,
                 float* __restrict__ out)
{
    __shared__ ushort Ks[F_BN * F_KS_STR];
    __shared__ ushort Ps[F_BM * F_P_STR];
    __shared__ float  mk[F_BN];
    __shared__ float  lpart[2][F_BM];
    __shared__ float  invs[F_BM];

    const int tid = threadIdx.x, lane = tid & 63, wave = tid >> 6;
    const int l31 = lane & 31, lh = lane >> 5;
    const int rw = wave >> 1, cw = wave & 1;
    const int batch = blockIdx.y, row0 = blockIdx.x * F_BM;
    const float* Xb = X + (size_t)batch * SEQ * DIM;
    const float* Yb = Y + (size_t)batch * SEQ * DIM;

    float4 kreg[16]; int mreg = 0;
    #pragma unroll
    for (int i = 0; i < 16; ++i) {
        int idx = tid + (i << 8); int r = idx >> 6, c4 = idx & 63;
        kreg[i] = *((const float4*)(Yb + (size_t)r * DIM) + c4);
    }
    if (tid < F_BN) mreg = my[batch * SEQ + tid];

    short8 qhi[16], qlo[16];
    {
        const float* qrow = Xb + (size_t)(row0 + rw * 32 + l31) * DIM + lh * 8;
        #pragma unroll
        for (int kk = 0; kk < 16; ++kk) {
            const float* p = qrow + kk * 16;
            float4 x0 = *(const float4*)p; float4 x1 = *(const float4*)(p + 4);
            float xs[8] = {x0.x, x0.y, x0.z, x0.w, x1.x, x1.y, x1.z, x1.w};
            #pragma unroll
            for (int j = 0; j < 8; ++j) {
                ushort h = bf16_rn(xs[j]);
                qhi[kk][j] = (short)h;
                qlo[kk][j] = (short)bf16_rn(xs[j] - bf16_to_f(h));
            }
        }
    }
    f32x16 oacc[4];
    #pragma unroll
    for (int t = 0; t < 4; ++t)
        #pragma unroll
        for (int r = 0; r < 16; ++r) oacc[t][r] = 0.f;
    float lsum[16];
    #pragma unroll
    for (int r = 0; r < 16; ++r) lsum[r] = 0.f;

    for (int nt = 0; nt < SEQ / F_BN; ++nt) {
        if (nt) __syncthreads();
        #pragma unroll
        for (int i = 0; i < 16; ++i) {
            int idx = tid + (i << 8); int r = idx >> 6, c4 = idx & 63;
            float f[4] = {kreg[i].x, kreg[i].y, kreg[i].z, kreg[i].w};
            ushort hh[4], ll[4];
            #pragma unroll
            for (int q = 0; q < 4; ++q) { hh[q] = bf16_rn(f[q]); ll[q] = bf16_rn(f[q] - bf16_to_f(hh[q])); }
            ushort4 hv; hv.x=hh[0];hv.y=hh[1];hv.z=hh[2];hv.w=hh[3];
            ushort4 lv; lv.x=ll[0];lv.y=ll[1];lv.z=ll[2];lv.w=ll[3];
            *(ushort4*)&Ks[r * F_KS_STR + c4 * 4] = hv;
            *(ushort4*)&Ks[r * F_KS_STR + 256 + c4 * 4] = lv;
        }
        if (tid < F_BN) mk[tid] = (float)mreg;
        __syncthreads();
        if (nt + 1 < SEQ / F_BN) {
            const float* Ybn = Yb + (size_t)(nt + 1) * F_BN * DIM;
            #pragma unroll
            for (int i = 0; i < 16; ++i) {
                int idx = tid + (i << 8); int r = idx >> 6, c4 = idx & 63;
                kreg[i] = *((const float4*)(Ybn + (size_t)r * DIM) + c4);
            }
            if (tid < F_BN) mreg = my[batch * SEQ + (nt + 1) * F_BN + tid];
        }
        f32x16 a1, a2, a3;
        #pragma unroll
        for (int r = 0; r < 16; ++r) { a1[r]=0.f; a2[r]=0.f; a3[r]=0.f; }
        const int krow = (cw * 32 + l31) * F_KS_STR;
        #pragma unroll
        for (int kk = 0; kk < 16; ++kk) {
            int col = kk * 16 + lh * 8;
            short8 bhi = *(const short8*)&Ks[krow + col];
            short8 blo = *(const short8*)&Ks[krow + 256 + col];
            a1 = __builtin_amdgcn_mfma_f32_32x32x16_bf16(qhi[kk], bhi, a1, 0, 0, 0);
            a2 = __builtin_amdgcn_mfma_f32_32x32x16_bf16(qlo[kk], bhi, a2, 0, 0, 0);
            a3 = __builtin_amdgcn_mfma_f32_32x32x16_bf16(qhi[kk], blo, a3, 0, 0, 0);
        }
        const float mkv = mk[cw * 32 + l31];
        #pragma unroll
        for (int r = 0; r < 16; ++r) {
            float s = a1[r] + a2[r] + a3[r];
            float p = __expf(s - SHIFT) * mkv;
            lsum[r] += p;
            ushort ph = bf16_rn(p);
            ushort pl = bf16_rn(p - bf16_to_f(ph));
            int prow = rw * 32 + (r & 3) + ((r >> 2) << 3) + (lh << 2);
            int pcol = cw * 32 + l31;
            Ps[prow * F_P_STR + pcol] = ph;
            Ps[prow * F_P_STR + 64 + pcol] = pl;
        }
        __syncthreads();
        const int prow = (rw * 32 + l31) * F_P_STR;
        #pragma unroll
        for (int kb = 0; kb < 4; ++kb) {
            int pcol = kb * 16 + lh * 8;
            short8 pa_hi = *(const short8*)&Ps[prow + pcol];
            short8 pa_lo = *(const short8*)&Ps[prow + 64 + pcol];
            #pragma unroll
            for (int t = 0; t < 4; ++t) {
                int d0 = cw * 128 + t * 32 + l31;
                short8 vf;
                #pragma unroll
                for (int j = 0; j < 8; ++j) vf[j] = (short)Ks[(pcol + j) * F_KS_STR + d0];
                oacc[t] = __builtin_amdgcn_mfma_f32_32x32x16_bf16(pa_hi, vf, oacc[t], 0, 0, 0);
                oacc[t] = __builtin_amdgcn_mfma_f32_32x32x16_bf16(pa_lo, vf, oacc[t], 0, 0, 0);
            }
        }
    }
    #pragma unroll
    for (int r = 0; r < 16; ++r) {
        float v = lsum[r];
        v += __shfl_xor(v, 1, 64); v += __shfl_xor(v, 2, 64); v += __shfl_xor(v, 4, 64);
        v += __shfl_xor(v, 8, 64); v += __shfl_xor(v, 16, 64);
        if (l31 == 0) {
            int row = rw * 32 + (r & 3) + ((r >> 2) << 3) + (lh << 2);
            lpart[cw][row] = v;
        }
    }
    __syncthreads();
    if (tid < F_BM) {
        float l = lpart[0][tid] + lpart[1][tid];
        int valid = mx[batch * SEQ + row0 + tid];
        invs[tid] = (valid != 0 && l > 0.f) ? 1.f / l : 0.f;
    }
    __syncthreads();
    float* ob = out + ((size_t)batch * SEQ + row0) * DIM;
    #pragma unroll
    for (int r = 0; r < 16; ++r) {
        int rloc = rw * 32 + (r & 3) + ((r >> 2) << 3) + (lh << 2);
        float inv = invs[rloc];
        #pragma unroll
        for (int t = 0; t < 4; ++t) {
            int d = cw * 128 + t * 32 + l31;
            ob[(size_t)rloc * DIM + d] = oacc[t][r] * inv;
        }
    }
}

extern "C" void kernel_launch(void* const* d_in, const int* in_sizes, int n_in,
                              void* d_out, int out_size, void* d_ws, size_t ws_size,
                              hipStream_t stream) {
    const float* a  = (const float*)d_in[0];
    const float* b  = (const float*)d_in[1];
    const int*   ma = (const int*)d_in[2];
    const int*   mb = (const int*)d_in[3];
    float* out = (float*)d_out;

    if (ws_size >= WS_NEED) {
        ushort* wsu = (ushort*)d_ws;
        ushort* aKc = wsu;
        ushort* bKc = wsu + KC_TENSOR;
        ushort* aT  = wsu + 2 * KC_TENSOR;
        ushort* bT  = wsu + 2 * KC_TENSOR + T_TENSOR;
        int* idxA  = (int*)(wsu + 2 * KC_TENSOR + 2 * T_TENSOR);
        int* idxB  = idxA + IDX_INTS;
        int* nvArr = idxB + IDX_INTS;

        compact<<<dim3(NB, 2), 1024, 0, stream>>>(ma, mb, idxA, idxB, nvArr);
        gatherK<<<dim3(128, NB, 2), 256, 0, stream>>>(a, b, idxA, idxB, nvArr, aKc, bKc);
        gatherT<<<dim3(128, NB, 2), 256, 0, stream>>>(a, b, idxA, idxB, nvArr, aT, bT);
        attend3<<<dim3(512, 1, 1), 512, 0, stream>>>(a, b, aKc, bKc, aT, bT,
                                                     nvArr, ma, mb, out);
    } else {
        float* out_a = out;
        float* out_b = out + (size_t)NB * SEQ * DIM;
        dim3 grid(SEQ / F_BM, NB), block(256);
        attend_mfma<<<grid, block, 0, stream>>>(a, b, ma, mb, out_a);
        attend_mfma<<<grid, block, 0, stream>>>(b, a, mb, ma, out_b);
    }
}

// Round 11
// 281.947 us; speedup vs baseline: 1.2729x; 1.2729x over previous
//
#include <hip/hip_runtime.h>
#include <math.h>
#include <stdint.h>

// SoftAttention B=32, L=1024, D=256 fp32 via split-bf16 MFMA flash attention.
// R14 = DUAL-SIDE COMPACTION. R13 falsified the uniform-duration/XCD theory
// (uniform tiles made FETCH worse, 226->394MB); R11 (most non-uniform) remains
// fastest. So: stop chasing fetch, cut work. Masked Q rows output exactly 0 ->
// compute only valid Q rows. Compacted tensors serve BOTH sides (R6's dual-use
// trick): cA (A in ma-compacted order) = Q-source for dir0 AND K-source for
// dir1; cB symmetric. attend3: Q read HL-style from cX (cheap bf16), K/V
// staged linearly, per-pair ntiles, blocks with row0>=nQ exit early, output
// pre-zeroed (zeroOut kernel) + epilogue scatter via idxX. Work ~0.28x of R6.

#define NB    32
#define SEQ   1024
#define DIM   256
#define BM    128
#define BN    64
#define SHIFT 60.0f
#define PS    1048   // Ph ushort stride per koct: b128-aligned, bank-spread

typedef unsigned int uint;
typedef unsigned short ushort;
typedef __attribute__((ext_vector_type(8)))  short short8;
typedef __attribute__((ext_vector_type(16))) float f32x16;

// ws layout (ushort units for tensors, then int arrays)
#define KC_BATCH  (64 * 1024 * 8)            // [dimoct64][ckey1024][8] (hi 0..31, lo 32..63)
#define KC_TENSOR ((size_t)NB * KC_BATCH)    // 32 MB
#define T_BATCH   (128 * 256 * 8)            // [ckeyoct128][dim256][8]
#define T_TENSOR  ((size_t)NB * T_BATCH)     // 16 MB
#define IDX_INTS  ((size_t)NB * SEQ)
#define WS_NEED   ((2 * KC_TENSOR + 2 * T_TENSOR) * sizeof(ushort) + (2 * IDX_INTS + 64) * sizeof(int))

__device__ __forceinline__ ushort bf16_rn(float x) {
    union { float f; uint u; } v; v.f = x;
    uint r = v.u + 0x7fffu + ((v.u >> 16) & 1u);
    return (ushort)(r >> 16);
}
__device__ __forceinline__ float bf16_to_f(ushort h) {
    union { uint u; float f; } v; v.u = ((uint)h) << 16;
    return v.f;
}
__device__ __forceinline__ void gl_lds16(const ushort* g, ushort* l) {
    __builtin_amdgcn_global_load_lds(
        (const __attribute__((address_space(1))) void*)g,
        (__attribute__((address_space(3))) void*)l, 16, 0, 0);
}

// ---------------- mask compaction: prefix-sum -> idx list + count ----------------
__global__ __launch_bounds__(1024)
void compact(const int* __restrict__ ma, const int* __restrict__ mb,
             int* __restrict__ idxA, int* __restrict__ idxB, int* __restrict__ nvArr)
{
    const int batch = blockIdx.x;
    const int t     = blockIdx.y;            // 0: ma->idxA, 1: mb->idxB
    const int* m = t ? mb : ma;
    int* idx = (t ? idxB : idxA) + batch * SEQ;
    const int tid = threadIdx.x;             // 0..1023
    const int lane = tid & 63, wv = tid >> 6;

    __shared__ int wsum[16];
    __shared__ int base[17];

    int v = (m[batch * SEQ + tid] != 0) ? 1 : 0;
    unsigned long long bal = __ballot(v);
    int lanePre = __popcll(bal & ((1ULL << lane) - 1ULL));
    if (lane == 0) wsum[wv] = __popcll(bal);
    __syncthreads();
    if (tid == 0) {
        int acc = 0;
        #pragma unroll
        for (int w = 0; w < 16; ++w) { base[w] = acc; acc += wsum[w]; }
        base[16] = acc;
        nvArr[t * NB + batch] = acc;
    }
    __syncthreads();
    if (v) idx[base[wv] + lanePre] = tid;
    if (tid >= base[16]) idx[tid] = 0;       // pad (guarded everywhere by nv)
}

// ---------------- gatherK: fp32 rows -> compacted hi/lo bf16 tensor ----------------
// block = one compacted oct (8 rows x 256 dims); thread=(oct 0..31, srow 0..7).
// Zero-fills rows >= nv (NaN-safe; padded Q rows never stored, padded K masked).
__global__ __launch_bounds__(256)
void gatherK(const float* __restrict__ A, const float* __restrict__ Bt,
             const int* __restrict__ idxA, const int* __restrict__ idxB,
             const int* __restrict__ nvArr,
             ushort* __restrict__ aKc, ushort* __restrict__ bKc)
{
    const int z     = blockIdx.z;            // 0: aKc from A/idxA, 1: bKc from B/idxB
    const int batch = blockIdx.y;
    const int soct  = blockIdx.x;            // 0..127 compacted oct
    const float* src = z ? Bt : A;
    const int* idx = (z ? idxB : idxA) + batch * SEQ;
    const int nv = nvArr[z * NB + batch];
    ushort* kcb = (z ? bKc : aKc) + (size_t)batch * KC_BATCH;

    const int tid = threadIdx.x;
    const int oct = tid >> 3, srow = tid & 7;
    const int c = soct * 8 + srow;           // compacted row index

    float xs[8] = {0.f, 0.f, 0.f, 0.f, 0.f, 0.f, 0.f, 0.f};
    if (c < nv) {
        const float* rp = src + ((size_t)batch * SEQ + idx[c]) * DIM + oct * 8;
        float4 x0 = *(const float4*)rp;
        float4 x1 = *(const float4*)(rp + 4);
        xs[0]=x0.x; xs[1]=x0.y; xs[2]=x0.z; xs[3]=x0.w;
        xs[4]=x1.x; xs[5]=x1.y; xs[6]=x1.z; xs[7]=x1.w;
    }
    short8 hv, lv;
    #pragma unroll
    for (int j = 0; j < 8; ++j) {
        ushort h = bf16_rn(xs[j]);
        hv[j] = (short)h;
        lv[j] = (short)bf16_rn(xs[j] - bf16_to_f(h));
    }
    *(short8*)(kcb + (size_t)oct * 8192 + (size_t)c * 8)        = hv;
    *(short8*)(kcb + (size_t)(oct + 32) * 8192 + (size_t)c * 8) = lv;
}

// ---------------- gatherT: V tensors (hi) in compacted key order ----------------
__global__ __launch_bounds__(256)
void gatherT(const float* __restrict__ A, const float* __restrict__ Bt,
             const int* __restrict__ idxA, const int* __restrict__ idxB,
             const int* __restrict__ nvArr,
             ushort* __restrict__ aT, ushort* __restrict__ bT)
{
    const int z     = blockIdx.z;
    const int batch = blockIdx.y;
    const int soct  = blockIdx.x;            // 0..127 (compacted)
    const float* src = z ? Bt : A;
    const int* idx = (z ? idxB : idxA) + batch * SEQ;
    const int nv = nvArr[z * NB + batch];
    ushort* tp = (z ? bT : aT) + (size_t)batch * T_BATCH + (size_t)soct * 2048;
    const int d = threadIdx.x;               // 0..255
    short8 hv;
    #pragma unroll
    for (int j = 0; j < 8; ++j) {
        int c = soct * 8 + j;
        float x = 0.f;
        if (c < nv) x = src[((size_t)batch * SEQ + idx[c]) * DIM + d];
        hv[j] = (short)bf16_rn(x);
    }
    *(short8*)(tp + (size_t)d * 8) = hv;
}

// ---------------- zeroOut: pre-zero the output (masked rows stay 0) ----------------
__global__ __launch_bounds__(256)
void zeroOut(float4* __restrict__ p, int n4)
{
    int i = blockIdx.x * 256 + threadIdx.x;
    const int stride = gridDim.x * 256;
    const float4 z = {0.f, 0.f, 0.f, 0.f};
    for (; i < n4; i += stride) p[i] = z;
}

// ---------------- main kernel: both directions, 512 threads, XCD-pinned ----------------
__global__ __launch_bounds__(512, 2)
void attend3(const ushort* __restrict__ aKc, const ushort* __restrict__ bKc,
             const ushort* __restrict__ aT,  const ushort* __restrict__ bT,
             const int*    __restrict__ idxA, const int* __restrict__ idxB,
             const int*    __restrict__ nvArr,
             float*        __restrict__ out)
{
    __shared__ __align__(16) ushort Ks2[64 * 512];   // [dimoct64][key64][8] 64 KB
    __shared__ __align__(16) ushort Vt2[8 * 2048];   // [koct8][dim256][8]   32 KB
    __shared__ __align__(16) ushort Ph[8 * PS];      // [koct8][qrow128][8]  16.4 KB
    __shared__ float lpart[2][BM];
    __shared__ float invs[BM];
    __shared__ int   oidx[BM];

    // XCD-pinning swizzle: all 8 row-blocks of one (batch,dir) pair share an XCD.
    const int bx   = blockIdx.x;        // 0..511
    const int xcd  = bx & 7;
    const int slot = bx >> 3;           // 0..63
    const int rb   = slot & 7;          // row-block 0..7
    const int pg   = slot >> 3;         // 0..7
    const int pair = xcd + 8 * pg;      // 0..63, pair%8 == xcd
    const int batch = pair >> 1;
    const int dir   = pair & 1;
    const int row0  = rb * BM;          // compacted Q-row base

    // dir0: Q = cA (ma-valid A rows), K/V = cB/tB (mb keys), scatter via idxA.
    // dir1: Q = cB, K/V = cA/tA, scatter via idxB.
    const ushort* qcY  = dir ? bKc  : aKc;
    const ushort* kcY  = dir ? aKc  : bKc;
    const ushort* tY   = dir ? aT   : bT;
    const int*    idxX = dir ? idxB : idxA;
    const int     nQ   = nvArr[(dir ? 1 : 0) * NB + batch];
    const int     nK   = nvArr[(dir ? 0 : 1) * NB + batch];
    const int     ntiles = (nK + BN - 1) >> 6;
    float* o = out + (size_t)dir * NB * SEQ * DIM;

    if (row0 >= nQ) return;             // no valid Q rows for this block

    const int tid  = threadIdx.x;
    const int lane = tid & 63;
    const int wave = tid >> 6;     // 0..7
    const int l31  = lane & 31;
    const int lh   = lane >> 5;
    const int rw   = wave >> 1;    // 0..3 (row block)
    const int cw   = wave & 1;     // 0..1 (key half / dim half)

    const ushort* qcYb = qcY + (size_t)batch * KC_BATCH;
    const ushort* kcYb = kcY + (size_t)batch * KC_BATCH;
    const ushort* tYb  = tY  + (size_t)batch * T_BATCH;

    // staging bases: wave w stages K dimocts w*8..w*8+7 and V koct w (all linear)
    const ushort* ksrc = kcYb + (size_t)(wave * 8) * 8192 + (size_t)lane * 8;
    ushort*       kdst = Ks2 + wave * 8 * 512 + lane * 8;
    const ushort* vsrc = tYb + (size_t)wave * 2048 + (size_t)lane * 8;
    ushort*       vdst = Vt2 + wave * 2048 + lane * 8;

    // issue K(0), V(0)
    #pragma unroll
    for (int i = 0; i < 8; ++i) gl_lds16(ksrc + (size_t)i * 8192, kdst + i * 512);
    #pragma unroll
    for (int i = 0; i < 4; ++i) gl_lds16(vsrc + i * 512, vdst + i * 512);

    // Q fragments (hi+lo) from compacted tensor, HL-style (cheap bf16 reads).
    // Rows >= nQ read zero-fill -> tiny p, never stored.
    const int qrow = row0 + rw * 32 + l31;  // compacted row
    short8 qhi[16], qlo[16];
    {
        const ushort* qb = qcYb + (size_t)lh * 8192 + (size_t)qrow * 8;
        #pragma unroll
        for (int kk = 0; kk < 16; ++kk) {
            qhi[kk] = *(const short8*)(qb + (size_t)(2 * kk) * 8192);
            qlo[kk] = *(const short8*)(qb + (size_t)(2 * kk + 32) * 8192);
        }
    }

    f32x16 oacc[4];
    #pragma unroll
    for (int t = 0; t < 4; ++t)
        #pragma unroll
        for (int r = 0; r < 16; ++r) oacc[t][r] = 0.f;
    float lsum[16];
    #pragma unroll
    for (int r = 0; r < 16; ++r) lsum[r] = 0.f;

    __syncthreads();   // drains K(0), V(0)

    for (int nt = 0; nt < ntiles; ++nt) {
        const int key0 = nt * BN;
        const float mkv = (key0 + cw * 32 + l31 < nK) ? 1.f : 0.f;

        // ---- S phase: a1 = Qhi·Khi ; a2 = Qlo·Khi + Qhi·Klo ----
        f32x16 a1, a2;
        #pragma unroll
        for (int r = 0; r < 16; ++r) { a1[r] = 0.f; a2[r] = 0.f; }
        const int kcol = (cw * 32 + l31) * 8;
        #pragma unroll
        for (int kk = 0; kk < 16; ++kk) {
            short8 bhi = *(const short8*)&Ks2[(2 * kk + lh) * 512 + kcol];
            a1 = __builtin_amdgcn_mfma_f32_32x32x16_bf16(qhi[kk], bhi, a1, 0, 0, 0);
            a2 = __builtin_amdgcn_mfma_f32_32x32x16_bf16(qlo[kk], bhi, a2, 0, 0, 0);
        }
        #pragma unroll
        for (int kk = 0; kk < 16; ++kk) {
            short8 blo = *(const short8*)&Ks2[(2 * kk + lh + 32) * 512 + kcol];
            a2 = __builtin_amdgcn_mfma_f32_32x32x16_bf16(qhi[kk], blo, a2, 0, 0, 0);
        }

        // ---- fixed-shift exp, l-partials, pack P-hi to LDS ----
        const int key  = cw * 32 + l31;
        const int koct = key >> 3, kj = key & 7;
        #pragma unroll
        for (int r = 0; r < 16; ++r) {
            float s = a1[r] + a2[r];
            float p = __expf(s - SHIFT) * mkv;
            lsum[r] += p;
            int qr = rw * 32 + (r & 3) + ((r >> 2) << 3) + (lh << 2);
            Ph[koct * PS + qr * 8 + kj] = bf16_rn(p);
        }
        __syncthreads();   // P visible; Ks2 free

        // prefetch K(nt+1) — linear compacted stream, flies during PV
        if (nt + 1 < ntiles) {
            const ushort* ks = ksrc + (size_t)(key0 + BN) * 8;
            #pragma unroll
            for (int i = 0; i < 8; ++i) gl_lds16(ks + (size_t)i * 8192, kdst + i * 512);
        }

        // ---- PV phase: oacc += Phi·Vhi ----
        const int prow = (rw * 32 + l31) * 8;
        #pragma unroll
        for (int kb = 0; kb < 4; ++kb) {
            short8 pa = *(const short8*)&Ph[(2 * kb + lh) * PS + prow];
            #pragma unroll
            for (int t = 0; t < 4; ++t) {
                int dim = cw * 128 + t * 32 + l31;
                short8 vf = *(const short8*)&Vt2[(2 * kb + lh) * 2048 + dim * 8];
                oacc[t] = __builtin_amdgcn_mfma_f32_32x32x16_bf16(pa, vf, oacc[t], 0, 0, 0);
            }
        }
        __syncthreads();   // Vt2/Ph free; drains K(nt+1)

        // prefetch V(nt+1) — flies during next S phase
        if (nt + 1 < ntiles) {
            const ushort* vs = vsrc + ((size_t)(key0 + BN) >> 3) * 2048;
            #pragma unroll
            for (int i = 0; i < 4; ++i) gl_lds16(vs + i * 512, vdst + i * 512);
        }
    }

    // ---- epilogue: reduce l, normalize, scatter-store to original rows ----
    #pragma unroll
    for (int r = 0; r < 16; ++r) {
        float v = lsum[r];
        v += __shfl_xor(v, 1, 64);
        v += __shfl_xor(v, 2, 64);
        v += __shfl_xor(v, 4, 64);
        v += __shfl_xor(v, 8, 64);
        v += __shfl_xor(v, 16, 64);
        if (l31 == 0) {
            int row = rw * 32 + (r & 3) + ((r >> 2) << 3) + (lh << 2);
            lpart[cw][row] = v;
        }
    }
    __syncthreads();
    if (tid < BM) {
        int crow = row0 + tid;
        float l = lpart[0][tid] + lpart[1][tid];
        int valid = (crow < nQ);
        invs[tid] = (valid && l > 0.f) ? 1.f / l : 0.f;
        oidx[tid] = valid ? idxX[batch * SEQ + crow] : 0;
    }
    __syncthreads();

    float* ob = o + (size_t)batch * SEQ * DIM;
    #pragma unroll
    for (int r = 0; r < 16; ++r) {
        int rloc = rw * 32 + (r & 3) + ((r >> 2) << 3) + (lh << 2);
        float inv = invs[rloc];
        if (inv != 0.f) {
            int orow = oidx[rloc];
            #pragma unroll
            for (int t = 0; t < 4; ++t) {
                int d = cw * 128 + t * 32 + l31;
                ob[(size_t)orow * DIM + d] = oacc[t][r] * inv;
            }
        }
    }
}

// ---------------- fallback (R2 kernel, known-good) if ws too small ----------------
#define F_KS_STR 520
#define F_P_STR  136
#define F_BM 64
#define F_BN 64
__global__ __launch_bounds__(256, 1)
void attend_mfma(const float* __restrict__ X, const float* __restrict__ Y,
                 const int* __restrict__ mx, const int* __restrict__ my,
                 float* __restrict__ out)
{
    __shared__ ushort Ks[F_BN * F_KS_STR];
    __shared__ ushort Ps[F_BM * F_P_STR];
    __shared__ float  mk[F_BN];
    __shared__ float  lpart[2][F_BM];
    __shared__ float  invs[F_BM];

    const int tid = threadIdx.x, lane = tid & 63, wave = tid >> 6;
    const int l31 = lane & 31, lh = lane >> 5;
    const int rw = wave >> 1, cw = wave & 1;
    const int batch = blockIdx.y, row0 = blockIdx.x * F_BM;
    const float* Xb = X + (size_t)batch * SEQ * DIM;
    const float* Yb = Y + (size_t)batch * SEQ * DIM;

    float4 kreg[16]; int mreg = 0;
    #pragma unroll
    for (int i = 0; i < 16; ++i) {
        int idx = tid + (i << 8); int r = idx >> 6, c4 = idx & 63;
        kreg[i] = *((const float4*)(Yb + (size_t)r * DIM) + c4);
    }
    if (tid < F_BN) mreg = my[batch * SEQ + tid];

    short8 qhi[16], qlo[16];
    {
        const float* qrow = Xb + (size_t)(row0 + rw * 32 + l31) * DIM + lh * 8;
        #pragma unroll
        for (int kk = 0; kk < 16; ++kk) {
            const float* p = qrow + kk * 16;
            float4 x0 = *(const float4*)p; float4 x1 = *(const float4*)(p + 4);
            float xs[8] = {x0.x, x0.y, x0.z, x0.w, x1.x, x1.y, x1.z, x1.w};
            #pragma unroll
            for (int j = 0; j < 8; ++j) {
                ushort h = bf16_rn(xs[j]);
                qhi[kk][j] = (short)h;
                qlo[kk][j] = (short)bf16_rn(xs[j] - bf16_to_f(h));
            }
        }
    }
    f32x16 oacc[4];
    #pragma unroll
    for (int t = 0; t < 4; ++t)
        #pragma unroll
        for (int r = 0; r < 16; ++r) oacc[t][r] = 0.f;
    float lsum[16];
    #pragma unroll
    for (int r = 0; r < 16; ++r) lsum[r] = 0.f;

    for (int nt = 0; nt < SEQ / F_BN; ++nt) {
        if (nt) __syncthreads();
        #pragma unroll
        for (int i = 0; i < 16; ++i) {
            int idx = tid + (i << 8); int r = idx >> 6, c4 = idx & 63;
            float f[4] = {kreg[i].x, kreg[i].y, kreg[i].z, kreg[i].w};
            ushort hh[4], ll[4];
            #pragma unroll
            for (int q = 0; q < 4; ++q) { hh[q] = bf16_rn(f[q]); ll[q] = bf16_rn(f[q] - bf16_to_f(hh[q])); }
            ushort4 hv; hv.x=hh[0];hv.y=hh[1];hv.z=hh[2];hv.w=hh[3];
            ushort4 lv; lv.x=ll[0];lv.y=ll[1];lv.z=ll[2];lv.w=ll[3];
            *(ushort4*)&Ks[r * F_KS_STR + c4 * 4] = hv;
            *(ushort4*)&Ks[r * F_KS_STR + 256 + c4 * 4] = lv;
        }
        if (tid < F_BN) mk[tid] = (float)mreg;
        __syncthreads();
        if (nt + 1 < SEQ / F_BN) {
            const float* Ybn = Yb + (size_t)(nt + 1) * F_BN * DIM;
            #pragma unroll
            for (int i = 0; i < 16; ++i) {
                int idx = tid + (i << 8); int r = idx >> 6, c4 = idx & 63;
                kreg[i] = *((const float4*)(Ybn + (size_t)r * DIM) + c4);
            }
            if (tid < F_BN) mreg = my[batch * SEQ + (nt + 1) * F_BN + tid];
        }
        f32x16 a1, a2, a3;
        #pragma unroll
        for (int r = 0; r < 16; ++r) { a1[r]=0.f; a2[r]=0.f; a3[r]=0.f; }
        const int krow = (cw * 32 + l31) * F_KS_STR;
        #pragma unroll
        for (int kk = 0; kk < 16; ++kk) {
            int col = kk * 16 + lh * 8;
            short8 bhi = *(const short8*)&Ks[krow + col];
            short8 blo = *(const short8*)&Ks[krow + 256 + col];
            a1 = __builtin_amdgcn_mfma_f32_32x32x16_bf16(qhi[kk], bhi, a1, 0, 0, 0);
            a2 = __builtin_amdgcn_mfma_f32_32x32x16_bf16(qlo[kk], bhi, a2, 0, 0, 0);
            a3 = __builtin_amdgcn_mfma_f32_32x32x16_bf16(qhi[kk], blo, a3, 0, 0, 0);
        }
        const float mkv = mk[cw * 32 + l31];
        #pragma unroll
        for (int r = 0; r < 16; ++r) {
            float s = a1[r] + a2[r] + a3[r];
            float p = __expf(s - SHIFT) * mkv;
            lsum[r] += p;
            ushort ph = bf16_rn(p);
            ushort pl = bf16_rn(p - bf16_to_f(ph));
            int prow = rw * 32 + (r & 3) + ((r >> 2) << 3) + (lh << 2);
            int pcol = cw * 32 + l31;
            Ps[prow * F_P_STR + pcol] = ph;
            Ps[prow * F_P_STR + 64 + pcol] = pl;
        }
        __syncthreads();
        const int prow = (rw * 32 + l31) * F_P_STR;
        #pragma unroll
        for (int kb = 0; kb < 4; ++kb) {
            int pcol = kb * 16 + lh * 8;
            short8 pa_hi = *(const short8*)&Ps[prow + pcol];
            short8 pa_lo = *(const short8*)&Ps[prow + 64 + pcol];
            #pragma unroll
            for (int t = 0; t < 4; ++t) {
                int d0 = cw * 128 + t * 32 + l31;
                short8 vf;
                #pragma unroll
                for (int j = 0; j < 8; ++j) vf[j] = (short)Ks[(pcol + j) * F_KS_STR + d0];
                oacc[t] = __builtin_amdgcn_mfma_f32_32x32x16_bf16(pa_hi, vf, oacc[t], 0, 0, 0);
                oacc[t] = __builtin_amdgcn_mfma_f32_32x32x16_bf16(pa_lo, vf, oacc[t], 0, 0, 0);
            }
        }
    }
    #pragma unroll
    for (int r = 0; r < 16; ++r) {
        float v = lsum[r];
        v += __shfl_xor(v, 1, 64); v += __shfl_xor(v, 2, 64); v += __shfl_xor(v, 4, 64);
        v += __shfl_xor(v, 8, 64); v += __shfl_xor(v, 16, 64);
        if (l31 == 0) {
            int row = rw * 32 + (r & 3) + ((r >> 2) << 3) + (lh << 2);
            lpart[cw][row] = v;
        }
    }
    __syncthreads();
    if (tid < F_BM) {
        float l = lpart[0][tid] + lpart[1][tid];
        int valid = mx[batch * SEQ + row0 + tid];
        invs[tid] = (valid != 0 && l > 0.f) ? 1.f / l : 0.f;
    }
    __syncthreads();
    float* ob = out + ((size_t)batch * SEQ + row0) * DIM;
    #pragma unroll
    for (int r = 0; r < 16; ++r) {
        int rloc = rw * 32 + (r & 3) + ((r >> 2) << 3) + (lh << 2);
        float inv = invs[rloc];
        #pragma unroll
        for (int t = 0; t < 4; ++t) {
            int d = cw * 128 + t * 32 + l31;
            ob[(size_t)rloc * DIM + d] = oacc[t][r] * inv;
        }
    }
}

extern "C" void kernel_launch(void* const* d_in, const int* in_sizes, int n_in,
                              void* d_out, int out_size, void* d_ws, size_t ws_size,
                              hipStream_t stream) {
    const float* a  = (const float*)d_in[0];
    const float* b  = (const float*)d_in[1];
    const int*   ma = (const int*)d_in[2];
    const int*   mb = (const int*)d_in[3];
    float* out = (float*)d_out;

    if (ws_size >= WS_NEED) {
        ushort* wsu = (ushort*)d_ws;
        ushort* aKc = wsu;
        ushort* bKc = wsu + KC_TENSOR;
        ushort* aT  = wsu + 2 * KC_TENSOR;
        ushort* bT  = wsu + 2 * KC_TENSOR + T_TENSOR;
        int* idxA  = (int*)(wsu + 2 * KC_TENSOR + 2 * T_TENSOR);
        int* idxB  = idxA + IDX_INTS;
        int* nvArr = idxB + IDX_INTS;

        compact<<<dim3(NB, 2), 1024, 0, stream>>>(ma, mb, idxA, idxB, nvArr);
        gatherK<<<dim3(128, NB, 2), 256, 0, stream>>>(a, b, idxA, idxB, nvArr, aKc, bKc);
        gatherT<<<dim3(128, NB, 2), 256, 0, stream>>>(a, b, idxA, idxB, nvArr, aT, bT);
        zeroOut<<<dim3(2048), 256, 0, stream>>>((float4*)out, out_size / 16);
        attend3<<<dim3(512, 1, 1), 512, 0, stream>>>(aKc, bKc, aT, bT,
                                                     idxA, idxB, nvArr, out);
    } else {
        float* out_a = out;
        float* out_b = out + (size_t)NB * SEQ * DIM;
        dim3 grid(SEQ / F_BM, NB), block(256);
        attend_mfma<<<grid, block, 0, stream>>>(a, b, ma, mb, out_a);
        attend_mfma<<<grid, block, 0, stream>>>(b, a, mb, ma, out_b);
    }
}

// Round 15
// 270.961 us; speedup vs baseline: 1.3246x; 1.0405x over previous
//
#include <hip/hip_runtime.h>
#include <math.h>
#include <stdint.h>

// SoftAttention B=32, L=1024, D=256 fp32 via split-bf16 MFMA flash attention.
// R15 = R14 (dual-side compaction, best: 281.9us total / 150.7us attend3) with
// prep consolidated; attend3 pipeline byte-identical except a prologue that
// zeroes masked ORIGINAL rows in each block's 128-row window (replaces the
// serial 64MB zeroOut kernel; zero-writes fly async under K/V staging; zero
// and scatter targets are disjoint). gatherKT merges gatherK+gatherT: rows
// read once into LDS, K hi/lo + transposed T emitted from there (saves 32MB
// re-read + a launch); write-guard at ntr=ceil(nv/64)*64 skips ~45% padding.
// attend3 makespan analysis (R14): ~288 items x ~75us on 256 CUs = 2 rounds
// = its structural floor; remaining fat was prep, addressed here.

#define NB    32
#define SEQ   1024
#define DIM   256
#define BM    128
#define BN    64
#define SHIFT 60.0f
#define PS    1048   // Ph ushort stride per koct: b128-aligned, bank-spread

typedef unsigned int uint;
typedef unsigned short ushort;
typedef __attribute__((ext_vector_type(8)))  short short8;
typedef __attribute__((ext_vector_type(16))) float f32x16;

// ws layout (ushort units for tensors, then int arrays)
#define KC_BATCH  (64 * 1024 * 8)            // [dimoct64][crow1024][8] (hi 0..31, lo 32..63)
#define KC_TENSOR ((size_t)NB * KC_BATCH)    // 32 MB
#define T_BATCH   (128 * 256 * 8)            // [crowoct128][dim256][8]
#define T_TENSOR  ((size_t)NB * T_BATCH)     // 16 MB
#define IDX_INTS  ((size_t)NB * SEQ)
#define WS_NEED   ((2 * KC_TENSOR + 2 * T_TENSOR) * sizeof(ushort) + (2 * IDX_INTS + 64) * sizeof(int))

__device__ __forceinline__ ushort bf16_rn(float x) {
    union { float f; uint u; } v; v.f = x;
    uint r = v.u + 0x7fffu + ((v.u >> 16) & 1u);
    return (ushort)(r >> 16);
}
__device__ __forceinline__ float bf16_to_f(ushort h) {
    union { uint u; float f; } v; v.u = ((uint)h) << 16;
    return v.f;
}
__device__ __forceinline__ void gl_lds16(const ushort* g, ushort* l) {
    __builtin_amdgcn_global_load_lds(
        (const __attribute__((address_space(1))) void*)g,
        (__attribute__((address_space(3))) void*)l, 16, 0, 0);
}

// ---------------- mask compaction: prefix-sum -> idx list + count ----------------
__global__ __launch_bounds__(1024)
void compact(const int* __restrict__ ma, const int* __restrict__ mb,
             int* __restrict__ idxA, int* __restrict__ idxB, int* __restrict__ nvArr)
{
    const int batch = blockIdx.x;
    const int t     = blockIdx.y;            // 0: ma->idxA, 1: mb->idxB
    const int* m = t ? mb : ma;
    int* idx = (t ? idxB : idxA) + batch * SEQ;
    const int tid = threadIdx.x;             // 0..1023
    const int lane = tid & 63, wv = tid >> 6;

    __shared__ int wsum[16];
    __shared__ int base[17];

    int v = (m[batch * SEQ + tid] != 0) ? 1 : 0;
    unsigned long long bal = __ballot(v);
    int lanePre = __popcll(bal & ((1ULL << lane) - 1ULL));
    if (lane == 0) wsum[wv] = __popcll(bal);
    __syncthreads();
    if (tid == 0) {
        int acc = 0;
        #pragma unroll
        for (int w = 0; w < 16; ++w) { base[w] = acc; acc += wsum[w]; }
        base[16] = acc;
        nvArr[t * NB + batch] = acc;
    }
    __syncthreads();
    if (v) idx[base[wv] + lanePre] = tid;
    if (tid >= base[16]) idx[tid] = 0;       // pad (guarded everywhere by nv)
}

// ---------------- gatherKT: compacted rows -> K hi/lo + transposed T ----------------
// block = one compacted oct (8 rows x 256 dims). Rows read ONCE (global->LDS);
// K hi/lo written linear, T written transposed from LDS. Zero-fill [nv, ntr);
// octs beyond ntr never read by attend3 -> early exit.
#define GSTR 264
__global__ __launch_bounds__(256)
void gatherKT(const float* __restrict__ A, const float* __restrict__ Bt,
              const int* __restrict__ idxA, const int* __restrict__ idxB,
              const int* __restrict__ nvArr,
              ushort* __restrict__ aKc, ushort* __restrict__ bKc,
              ushort* __restrict__ aT,  ushort* __restrict__ bT)
{
    const int z     = blockIdx.z;            // 0: from A/idxA, 1: from B/idxB
    const int batch = blockIdx.y;
    const int soct  = blockIdx.x;            // 0..127 compacted oct
    const float* src = z ? Bt : A;
    const int* idx = (z ? idxB : idxA) + batch * SEQ;
    const int nv = nvArr[z * NB + batch];
    const int ntr = (nv + 63) & ~63;         // rows attend3 will actually read
    if (soct * 8 >= ntr) return;

    ushort* kcb = (z ? bKc : aKc) + (size_t)batch * KC_BATCH;
    ushort* tp  = ((z ? bT : aT) + (size_t)batch * T_BATCH) + (size_t)soct * 2048;

    __shared__ float tile[8 * GSTR];

    const int tid = threadIdx.x;
    const int oct = tid >> 3, srow = tid & 7;
    const int c = soct * 8 + srow;           // compacted row index

    float xs[8] = {0.f, 0.f, 0.f, 0.f, 0.f, 0.f, 0.f, 0.f};
    if (c < nv) {
        const float* rp = src + ((size_t)batch * SEQ + idx[c]) * DIM + oct * 8;
        float4 x0 = *(const float4*)rp;
        float4 x1 = *(const float4*)(rp + 4);
        xs[0]=x0.x; xs[1]=x0.y; xs[2]=x0.z; xs[3]=x0.w;
        xs[4]=x1.x; xs[5]=x1.y; xs[6]=x1.z; xs[7]=x1.w;
    }
    short8 hv, lv;
    #pragma unroll
    for (int j = 0; j < 8; ++j) {
        ushort h = bf16_rn(xs[j]);
        hv[j] = (short)h;
        lv[j] = (short)bf16_rn(xs[j] - bf16_to_f(h));
        tile[srow * GSTR + oct * 8 + j] = xs[j];
    }
    *(short8*)(kcb + (size_t)oct * 8192 + (size_t)c * 8)        = hv;
    *(short8*)(kcb + (size_t)(oct + 32) * 8192 + (size_t)c * 8) = lv;

    __syncthreads();
    {
        const int d = tid;                   // 0..255
        short8 tv;
        #pragma unroll
        for (int j = 0; j < 8; ++j)
            tv[j] = (short)bf16_rn(tile[j * GSTR + d]);
        *(short8*)(tp + (size_t)d * 8) = tv;
    }
}

// ---------------- main kernel: both directions, 512 threads, XCD-pinned ----------------
__global__ __launch_bounds__(512, 2)
void attend3(const ushort* __restrict__ aKc, const ushort* __restrict__ bKc,
             const ushort* __restrict__ aT,  const ushort* __restrict__ bT,
             const int*    __restrict__ idxA, const int* __restrict__ idxB,
             const int*    __restrict__ nvArr,
             const int*    __restrict__ ma,  const int*    __restrict__ mb,
             float*        __restrict__ out)
{
    __shared__ __align__(16) ushort Ks2[64 * 512];   // [dimoct64][key64][8] 64 KB
    __shared__ __align__(16) ushort Vt2[8 * 2048];   // [koct8][dim256][8]   32 KB
    __shared__ __align__(16) ushort Ph[8 * PS];      // [koct8][qrow128][8]  16.4 KB
    __shared__ float lpart[2][BM];
    __shared__ float invs[BM];
    __shared__ int   oidx[BM];

    // XCD-pinning swizzle: all 8 row-blocks of one (batch,dir) pair share an XCD.
    const int bx   = blockIdx.x;        // 0..511
    const int xcd  = bx & 7;
    const int slot = bx >> 3;           // 0..63
    const int rb   = slot & 7;          // row-block 0..7
    const int pg   = slot >> 3;         // 0..7
    const int pair = xcd + 8 * pg;      // 0..63, pair%8 == xcd
    const int batch = pair >> 1;
    const int dir   = pair & 1;
    const int row0  = rb * BM;          // compacted Q-row base

    // dir0: Q = cA (ma-valid A rows), K/V = cB/tB (mb keys), scatter via idxA.
    // dir1: Q = cB, K/V = cA/tA, scatter via idxB.
    const ushort* qcY  = dir ? bKc  : aKc;
    const ushort* kcY  = dir ? aKc  : bKc;
    const ushort* tY   = dir ? aT   : bT;
    const int*    idxX = dir ? idxB : idxA;
    const int*    mq   = dir ? mb   : ma;    // Q-side mask (original rows)
    const int     nQ   = nvArr[(dir ? 1 : 0) * NB + batch];
    const int     nK   = nvArr[(dir ? 0 : 1) * NB + batch];
    const int     ntiles = (nK + BN - 1) >> 6;
    float* o = out + (size_t)dir * NB * SEQ * DIM;

    const int tid  = threadIdx.x;

    // Zero masked ORIGINAL rows in this block's 128-row window (replaces
    // zeroOut). 4 threads/row x 64 floats. Disjoint from scatter targets.
    {
        float* ob0 = o + (size_t)batch * SEQ * DIM;
        const int orow = rb * BM + (tid >> 2);
        if (mq[batch * SEQ + orow] == 0) {
            float4* p = (float4*)(ob0 + (size_t)orow * DIM + (tid & 3) * 64);
            const float4 zz = {0.f, 0.f, 0.f, 0.f};
            #pragma unroll
            for (int i = 0; i < 16; ++i) p[i] = zz;
        }
    }

    if (row0 >= nQ) return;             // no valid Q rows for this block

    const int lane = tid & 63;
    const int wave = tid >> 6;     // 0..7
    const int l31  = lane & 31;
    const int lh   = lane >> 5;
    const int rw   = wave >> 1;    // 0..3 (row block)
    const int cw   = wave & 1;     // 0..1 (key half / dim half)

    const ushort* qcYb = qcY + (size_t)batch * KC_BATCH;
    const ushort* kcYb = kcY + (size_t)batch * KC_BATCH;
    const ushort* tYb  = tY  + (size_t)batch * T_BATCH;

    // staging bases: wave w stages K dimocts w*8..w*8+7 and V koct w (all linear)
    const ushort* ksrc = kcYb + (size_t)(wave * 8) * 8192 + (size_t)lane * 8;
    ushort*       kdst = Ks2 + wave * 8 * 512 + lane * 8;
    const ushort* vsrc = tYb + (size_t)wave * 2048 + (size_t)lane * 8;
    ushort*       vdst = Vt2 + wave * 2048 + lane * 8;

    // issue K(0), V(0)
    #pragma unroll
    for (int i = 0; i < 8; ++i) gl_lds16(ksrc + (size_t)i * 8192, kdst + i * 512);
    #pragma unroll
    for (int i = 0; i < 4; ++i) gl_lds16(vsrc + i * 512, vdst + i * 512);

    // Q fragments (hi+lo) from compacted tensor, HL-style (cheap bf16 reads).
    // Rows >= nQ read zero-fill -> tiny p, never stored.
    const int qrow = row0 + rw * 32 + l31;  // compacted row
    short8 qhi[16], qlo[16];
    {
        const ushort* qb = qcYb + (size_t)lh * 8192 + (size_t)qrow * 8;
        #pragma unroll
        for (int kk = 0; kk < 16; ++kk) {
            qhi[kk] = *(const short8*)(qb + (size_t)(2 * kk) * 8192);
            qlo[kk] = *(const short8*)(qb + (size_t)(2 * kk + 32) * 8192);
        }
    }

    f32x16 oacc[4];
    #pragma unroll
    for (int t = 0; t < 4; ++t)
        #pragma unroll
        for (int r = 0; r < 16; ++r) oacc[t][r] = 0.f;
    float lsum[16];
    #pragma unroll
    for (int r = 0; r < 16; ++r) lsum[r] = 0.f;

    __syncthreads();   // drains K(0), V(0)

    for (int nt = 0; nt < ntiles; ++nt) {
        const int key0 = nt * BN;
        const float mkv = (key0 + cw * 32 + l31 < nK) ? 1.f : 0.f;

        // ---- S phase: a1 = Qhi·Khi ; a2 = Qlo·Khi + Qhi·Klo ----
        f32x16 a1, a2;
        #pragma unroll
        for (int r = 0; r < 16; ++r) { a1[r] = 0.f; a2[r] = 0.f; }
        const int kcol = (cw * 32 + l31) * 8;
        #pragma unroll
        for (int kk = 0; kk < 16; ++kk) {
            short8 bhi = *(const short8*)&Ks2[(2 * kk + lh) * 512 + kcol];
            a1 = __builtin_amdgcn_mfma_f32_32x32x16_bf16(qhi[kk], bhi, a1, 0, 0, 0);
            a2 = __builtin_amdgcn_mfma_f32_32x32x16_bf16(qlo[kk], bhi, a2, 0, 0, 0);
        }
        #pragma unroll
        for (int kk = 0; kk < 16; ++kk) {
            short8 blo = *(const short8*)&Ks2[(2 * kk + lh + 32) * 512 + kcol];
            a2 = __builtin_amdgcn_mfma_f32_32x32x16_bf16(qhi[kk], blo, a2, 0, 0, 0);
        }

        // ---- fixed-shift exp, l-partials, pack P-hi to LDS ----
        const int key  = cw * 32 + l31;
        const int koct = key >> 3, kj = key & 7;
        #pragma unroll
        for (int r = 0; r < 16; ++r) {
            float s = a1[r] + a2[r];
            float p = __expf(s - SHIFT) * mkv;
            lsum[r] += p;
            int qr = rw * 32 + (r & 3) + ((r >> 2) << 3) + (lh << 2);
            Ph[koct * PS + qr * 8 + kj] = bf16_rn(p);
        }
        __syncthreads();   // P visible; Ks2 free

        // prefetch K(nt+1) — linear compacted stream, flies during PV
        if (nt + 1 < ntiles) {
            const ushort* ks = ksrc + (size_t)(key0 + BN) * 8;
            #pragma unroll
            for (int i = 0; i < 8; ++i) gl_lds16(ks + (size_t)i * 8192, kdst + i * 512);
        }

        // ---- PV phase: oacc += Phi·Vhi ----
        const int prow = (rw * 32 + l31) * 8;
        #pragma unroll
        for (int kb = 0; kb < 4; ++kb) {
            short8 pa = *(const short8*)&Ph[(2 * kb + lh) * PS + prow];
            #pragma unroll
            for (int t = 0; t < 4; ++t) {
                int dim = cw * 128 + t * 32 + l31;
                short8 vf = *(const short8*)&Vt2[(2 * kb + lh) * 2048 + dim * 8];
                oacc[t] = __builtin_amdgcn_mfma_f32_32x32x16_bf16(pa, vf, oacc[t], 0, 0, 0);
            }
        }
        __syncthreads();   // Vt2/Ph free; drains K(nt+1)

        // prefetch V(nt+1) — flies during next S phase
        if (nt + 1 < ntiles) {
            const ushort* vs = vsrc + ((size_t)(key0 + BN) >> 3) * 2048;
            #pragma unroll
            for (int i = 0; i < 4; ++i) gl_lds16(vs + i * 512, vdst + i * 512);
        }
    }

    // ---- epilogue: reduce l, normalize, scatter-store to original rows ----
    #pragma unroll
    for (int r = 0; r < 16; ++r) {
        float v = lsum[r];
        v += __shfl_xor(v, 1, 64);
        v += __shfl_xor(v, 2, 64);
        v += __shfl_xor(v, 4, 64);
        v += __shfl_xor(v, 8, 64);
        v += __shfl_xor(v, 16, 64);
        if (l31 == 0) {
            int row = rw * 32 + (r & 3) + ((r >> 2) << 3) + (lh << 2);
            lpart[cw][row] = v;
        }
    }
    __syncthreads();
    if (tid < BM) {
        int crow = row0 + tid;
        float l = lpart[0][tid] + lpart[1][tid];
        int valid = (crow < nQ);
        invs[tid] = (valid && l > 0.f) ? 1.f / l : 0.f;
        oidx[tid] = valid ? idxX[batch * SEQ + crow] : 0;
    }
    __syncthreads();

    float* ob = o + (size_t)batch * SEQ * DIM;
    #pragma unroll
    for (int r = 0; r < 16; ++r) {
        int rloc = rw * 32 + (r & 3) + ((r >> 2) << 3) + (lh << 2);
        float inv = invs[rloc];
        if (inv != 0.f) {
            int orow = oidx[rloc];
            #pragma unroll
            for (int t = 0; t < 4; ++t) {
                int d = cw * 128 + t * 32 + l31;
                ob[(size_t)orow * DIM + d] = oacc[t][r] * inv;
            }
        }
    }
}

// ---------------- fallback (R2 kernel, known-good) if ws too small ----------------
#define F_KS_STR 520
#define F_P_STR  136
#define F_BM 64
#define F_BN 64
__global__ __launch_bounds__(256, 1)
void attend_mfma(const float* __restrict__ X, const float* __restrict__ Y,
                 const int* __restrict__ mx, const int* __restrict__ my,
                 float* __restrict__ out)
{
    __shared__ ushort Ks[F_BN * F_KS_STR];
    __shared__ ushort Ps[F_BM * F_P_STR];
    __shared__ float  mk[F_BN];
    __shared__ float  lpart[2][F_BM];
    __shared__ float  invs[F_BM];

    const int tid = threadIdx.x, lane = tid & 63, wave = tid >> 6;
    const int l31 = lane & 31, lh = lane >> 5;
    const int rw = wave >> 1, cw = wave & 1;
    const int batch = blockIdx.y, row0 = blockIdx.x * F_BM;
    const float* Xb = X + (size_t)batch * SEQ * DIM;
    const float* Yb = Y + (size_t)batch * SEQ * DIM;

    float4 kreg[16]; int mreg = 0;
    #pragma unroll
    for (int i = 0; i < 16; ++i) {
        int idx = tid + (i << 8); int r = idx >> 6, c4 = idx & 63;
        kreg[i] = *((const float4*)(Yb + (size_t)r * DIM) + c4);
    }
    if (tid < F_BN) mreg = my[batch * SEQ + tid];

    short8 qhi[16], qlo[16];
    {
        const float* qrow = Xb + (size_t)(row0 + rw * 32 + l31) * DIM + lh * 8;
        #pragma unroll
        for (int kk = 0; kk < 16; ++kk) {
            const float* p = qrow + kk * 16;
            float4 x0 = *(const float4*)p; float4 x1 = *(const float4*)(p + 4);
            float xs[8] = {x0.x, x0.y, x0.z, x0.w, x1.x, x1.y, x1.z, x1.w};
            #pragma unroll
            for (int j = 0; j < 8; ++j) {
                ushort h = bf16_rn(xs[j]);
                qhi[kk][j] = (short)h;
                qlo[kk][j] = (short)bf16_rn(xs[j] - bf16_to_f(h));
            }
        }
    }
    f32x16 oacc[4];
    #pragma unroll
    for (int t = 0; t < 4; ++t)
        #pragma unroll
        for (int r = 0; r < 16; ++r) oacc[t][r] = 0.f;
    float lsum[16];
    #pragma unroll
    for (int r = 0; r < 16; ++r) lsum[r] = 0.f;

    for (int nt = 0; nt < SEQ / F_BN; ++nt) {
        if (nt) __syncthreads();
        #pragma unroll
        for (int i = 0; i < 16; ++i) {
            int idx = tid + (i << 8); int r = idx >> 6, c4 = idx & 63;
            float f[4] = {kreg[i].x, kreg[i].y, kreg[i].z, kreg[i].w};
            ushort hh[4], ll[4];
            #pragma unroll
            for (int q = 0; q < 4; ++q) { hh[q] = bf16_rn(f[q]); ll[q] = bf16_rn(f[q] - bf16_to_f(hh[q])); }
            ushort4 hv; hv.x=hh[0];hv.y=hh[1];hv.z=hh[2];hv.w=hh[3];
            ushort4 lv; lv.x=ll[0];lv.y=ll[1];lv.z=ll[2];lv.w=ll[3];
            *(ushort4*)&Ks[r * F_KS_STR + c4 * 4] = hv;
            *(ushort4*)&Ks[r * F_KS_STR + 256 + c4 * 4] = lv;
        }
        if (tid < F_BN) mk[tid] = (float)mreg;
        __syncthreads();
        if (nt + 1 < SEQ / F_BN) {
            const float* Ybn = Yb + (size_t)(nt + 1) * F_BN * DIM;
            #pragma unroll
            for (int i = 0; i < 16; ++i) {
                int idx = tid + (i << 8); int r = idx >> 6, c4 = idx & 63;
                kreg[i] = *((const float4*)(Ybn + (size_t)r * DIM) + c4);
            }
            if (tid < F_BN) mreg = my[batch * SEQ + (nt + 1) * F_BN + tid];
        }
        f32x16 a1, a2, a3;
        #pragma unroll
        for (int r = 0; r < 16; ++r) { a1[r]=0.f; a2[r]=0.f; a3[r]=0.f; }
        const int krow = (cw * 32 + l31) * F_KS_STR;
        #pragma unroll
        for (int kk = 0; kk < 16; ++kk) {
            int col = kk * 16 + lh * 8;
            short8 bhi = *(const short8*)&Ks[krow + col];
            short8 blo = *(const short8*)&Ks[krow + 256 + col];
            a1 = __builtin_amdgcn_mfma_f32_32x32x16_bf16(qhi[kk], bhi, a1, 0, 0, 0);
            a2 = __builtin_amdgcn_mfma_f32_32x32x16_bf16(qlo[kk], bhi, a2, 0, 0, 0);
            a3 = __builtin_amdgcn_mfma_f32_32x32x16_bf16(qhi[kk], blo, a3, 0, 0, 0);
        }
        const float mkv = mk[cw * 32 + l31];
        #pragma unroll
        for (int r = 0; r < 16; ++r) {
            float s = a1[r] + a2[r] + a3[r];
            float p = __expf(s - SHIFT) * mkv;
            lsum[r] += p;
            ushort ph = bf16_rn(p);
            ushort pl = bf16_rn(p - bf16_to_f(ph));
            int prow = rw * 32 + (r & 3) + ((r >> 2) << 3) + (lh << 2);
            int pcol = cw * 32 + l31;
            Ps[prow * F_P_STR + pcol] = ph;
            Ps[prow * F_P_STR + 64 + pcol] = pl;
        }
        __syncthreads();
        const int prow = (rw * 32 + l31) * F_P_STR;
        #pragma unroll
        for (int kb = 0; kb < 4; ++kb) {
            int pcol = kb * 16 + lh * 8;
            short8 pa_hi = *(const short8*)&Ps[prow + pcol];
            short8 pa_lo = *(const short8*)&Ps[prow + 64 + pcol];
            #pragma unroll
            for (int t = 0; t < 4; ++t) {
                int d0 = cw * 128 + t * 32 + l31;
                short8 vf;
                #pragma unroll
                for (int j = 0; j < 8; ++j) vf[j] = (short)Ks[(pcol + j) * F_KS_STR + d0];
                oacc[t] = __builtin_amdgcn_mfma_f32_32x32x16_bf16(pa_hi, vf, oacc[t], 0, 0, 0);
                oacc[t] = __builtin_amdgcn_mfma_f32_32x32x16_bf16(pa_lo, vf, oacc[t], 0, 0, 0);
            }
        }
    }
    #pragma unroll
    for (int r = 0; r < 16; ++r) {
        float v = lsum[r];
        v += __shfl_xor(v, 1, 64); v += __shfl_xor(v, 2, 64); v += __shfl_xor(v, 4, 64);
        v += __shfl_xor(v, 8, 64); v += __shfl_xor(v, 16, 64);
        if (l31 == 0) {
            int row = rw * 32 + (r & 3) + ((r >> 2) << 3) + (lh << 2);
            lpart[cw][row] = v;
        }
    }
    __syncthreads();
    if (tid < F_BM) {
        float l = lpart[0][tid] + lpart[1][tid];
        int valid = mx[batch * SEQ + row0 + tid];
        invs[tid] = (valid != 0 && l > 0.f) ? 1.f / l : 0.f;
    }
    __syncthreads();
    float* ob = out + ((size_t)batch * SEQ + row0) * DIM;
    #pragma unroll
    for (int r = 0; r < 16; ++r) {
        int rloc = rw * 32 + (r & 3) + ((r >> 2) << 3) + (lh << 2);
        float inv = invs[rloc];
        #pragma unroll
        for (int t = 0; t < 4; ++t) {
            int d = cw * 128 + t * 32 + l31;
            ob[(size_t)rloc * DIM + d] = oacc[t][r] * inv;
        }
    }
}

extern "C" void kernel_launch(void* const* d_in, const int* in_sizes, int n_in,
                              void* d_out, int out_size, void* d_ws, size_t ws_size,
                              hipStream_t stream) {
    const float* a  = (const float*)d_in[0];
    const float* b  = (const float*)d_in[1];
    const int*   ma = (const int*)d_in[2];
    const int*   mb = (const int*)d_in[3];
    float* out = (float*)d_out;

    if (ws_size >= WS_NEED) {
        ushort* wsu = (ushort*)d_ws;
        ushort* aKc = wsu;
        ushort* bKc = wsu + KC_TENSOR;
        ushort* aT  = wsu + 2 * KC_TENSOR;
        ushort* bT  = wsu + 2 * KC_TENSOR + T_TENSOR;
        int* idxA  = (int*)(wsu + 2 * KC_TENSOR + 2 * T_TENSOR);
        int* idxB  = idxA + IDX_INTS;
        int* nvArr = idxB + IDX_INTS;

        compact<<<dim3(NB, 2), 1024, 0, stream>>>(ma, mb, idxA, idxB, nvArr);
        gatherKT<<<dim3(128, NB, 2), 256, 0, stream>>>(a, b, idxA, idxB, nvArr,
                                                       aKc, bKc, aT, bT);
        attend3<<<dim3(512, 1, 1), 512, 0, stream>>>(aKc, bKc, aT, bT,
                                                     idxA, idxB, nvArr, ma, mb, out);
    } else {
        float* out_a = out;
        float* out_b = out + (size_t)NB * SEQ * DIM;
        dim3 grid(SEQ / F_BM, NB), block(256);
        attend_mfma<<<grid, block, 0, stream>>>(a, b, ma, mb, out_a);
        attend_mfma<<<grid, block, 0, stream>>>(b, a, mb, ma, out_b);
    }
}